// Round 15
// baseline (277.420 us; speedup 1.0000x reference)
//
#include <hip/hip_runtime.h>
#include <hip/hip_cooperative_groups.h>

namespace cg = cooperative_groups;

#define GATE_SCALE 1.7015f
#define SX 32.0f
#define SW 1024.0f
#define DESCALE 3.0517578125e-05f   // 1/(SX*SW) = 2^-15

typedef __attribute__((ext_vector_type(4))) int   v4i;
typedef __attribute__((ext_vector_type(16))) int  v16i;

__device__ __forceinline__ void gl2lds16(const void* g, void* l) {
    __builtin_amdgcn_global_load_lds((const __attribute__((address_space(1))) void*)g,
                                     (__attribute__((address_space(3))) void*)l, 16, 0, 0);
}

__device__ __forceinline__ int q8(float v, float s) {
    int q = __float2int_rn(v * s);
    return q < -127 ? -127 : (q > 127 ? 127 : q);
}

// ===========================================================================
// Shared device bodies (used by both the mega kernel and the fallback path)
// ===========================================================================

// Phase A body: grid-stride quantize (12 iters at 131072 threads) + Ac tail.
__device__ __forceinline__ void phaseA(int gtid,
                                       const float* __restrict__ xr, const float* __restrict__ xi,
                                       const float* __restrict__ W,
                                       const float* __restrict__ Ar, const float* __restrict__ Ai,
                                       signed char* __restrict__ xq, signed char* __restrict__ wq,
                                       float* __restrict__ Ac) {
    if (gtid < 8192) {
        int n = gtid >> 6, t = gtid & 63, o = t >> 3, i = t & 7;
        const float* arn = Ar + n * 64;
        const float* ain = Ai + n * 64;
        float a_r = 0.5f * (arn[o * 8 + i] - arn[i * 8 + o]);
        float a_i = 0.5f * (ain[o * 8 + i] + ain[i * 8 + o]);
        Ac[n * 128 + t * 2]     = a_r;
        Ac[n * 128 + t * 2 + 1] = a_i;
    }
    const int XCV = 2048 * 2048 / 4;         // 1048576
    #pragma unroll
    for (int it = 0; it < 12; ++it) {        // 12*131072 == 1572864 exactly
        int v = it * 131072 + gtid;
        float4 f;
        signed char* dst;
        float s;
        if (v < XCV) {
            int idx = v * 4;
            int m = idx >> 11;
            int k = idx & 2047;
            const float* src = (k < 1024) ? (xr + m * 1024 + k)
                                          : (xi + m * 1024 + k - 1024);
            f = *(const float4*)src;
            dst = xq + idx;
            s = SX;
        } else {
            int idx = (v - XCV) * 4;
            f = *(const float4*)(W + idx);
            dst = wq + idx;
            s = SW;
        }
        int a = q8(f.x, s), b = q8(f.y, s), c = q8(f.z, s), d = q8(f.w, s);
        unsigned int packed = (a & 0xFF) | ((b & 0xFF) << 8) | ((c & 0xFF) << 16)
                            | ((unsigned)(d & 0xFF) << 24);
        *(unsigned int*)dst = packed;
    }
}

// Phase B body: R12's proven i8 GEMM (4 waves, 64x64, BK=128B, ring-4,
// counted vmcnt(8), raw barriers, setprio, XCD-rectangle swizzle).
// lA/lB are the block's 64 KB LDS (4 x 8 KB each).
__device__ __forceinline__ void phaseB(int bid, int tid,
                                       signed char (*lA)[64 * 128], signed char (*lB)[64 * 128],
                                       const signed char* __restrict__ A,
                                       const signed char* __restrict__ Bw,
                                       const float* __restrict__ bias,
                                       float* __restrict__ g) {
    const int lane = tid & 63;
    const int wid = tid >> 6;                 // 0..3
    const int x = bid & 7, l = bid >> 3;
    const int m0 = ((x & 3) * 8 + (l & 7)) * 64;
    const int n0 = ((x >> 2) * 8 + (l >> 3)) * 64;
    const int wr = wid >> 1, wc = wid & 1;
    const int lo = lane & 31, hi = lane >> 5, lo3 = lane & 7;
    const int arow = wr * 32 + lo, brow = wc * 32 + lo;
    const int ar7 = arow & 7, br7 = brow & 7;

    v16i acc = {};

    #define STAGE(buf, k0)                                                          \
        {                                                                           \
            _Pragma("unroll")                                                       \
            for (int q = 0; q < 2; ++q) {                                           \
                int c = q * 256 + tid;                                              \
                int row = c >> 3, ks = (c & 7) ^ (row & 7);                         \
                gl2lds16(&A[(m0 + row) * 2048 + (k0) + ks * 16], &lA[buf][c * 16]); \
            }                                                                       \
            _Pragma("unroll")                                                       \
            for (int q = 0; q < 2; ++q) {                                           \
                int c = q * 256 + tid;                                              \
                int row = c >> 3, ks = (c & 7) ^ (row & 7);                         \
                gl2lds16(&Bw[(n0 + row) * 2048 + (k0) + ks * 16], &lB[buf][c * 16]);\
            }                                                                       \
        }

    #define TILE(t, vmstr, do_stage)                                               \
        {                                                                           \
            asm volatile("s_waitcnt vmcnt(" vmstr ")" ::: "memory");                \
            __builtin_amdgcn_s_barrier();                                           \
            const int b = (t) & 3;                                                  \
            v4i af[4], bf[4];                                                       \
            _Pragma("unroll")                                                       \
            for (int kk = 0; kk < 4; ++kk) {                                        \
                const int ch = ((2 * kk + hi) ^ ar7) << 4;                          \
                const int chb = ((2 * kk + hi) ^ br7) << 4;                         \
                af[kk] = *(const v4i*)&lA[b][arow * 128 + ch];                      \
                bf[kk] = *(const v4i*)&lB[b][brow * 128 + chb];                     \
            }                                                                       \
            if (do_stage) STAGE((((t) + 3) & 3), ((t) + 3) * 128);                  \
            __builtin_amdgcn_s_setprio(1);                                          \
            _Pragma("unroll")                                                       \
            for (int kk = 0; kk < 4; ++kk)                                          \
                acc = __builtin_amdgcn_mfma_i32_32x32x32_i8(af[kk], bf[kk], acc, 0, 0, 0); \
            __builtin_amdgcn_s_setprio(0);                                          \
        }

    STAGE(0, 0);
    STAGE(1, 128);
    STAGE(2, 256);
    for (int t = 0; t < 13; ++t) TILE(t, "8", true);
    TILE(13, "8", false);
    TILE(14, "4", false);
    TILE(15, "0", false);
    #undef TILE
    #undef STAGE

    const int ncol = n0 + wc * 32 + lo;
    const float bv = bias[ncol];
    const int gcol = ncol >> 3;
    #pragma unroll
    for (int r = 0; r < 16; ++r) {
        const int mrow = m0 + wr * 32 + (r & 3) + 8 * (r >> 2) + 4 * hi;
        float z = ((float)acc[r] * DESCALE + bv) * GATE_SCALE;
        float gate = 1.0f / (1.0f + __expf(-z));
        gate += __shfl_xor(gate, 1);
        gate += __shfl_xor(gate, 2);
        gate += __shfl_xor(gate, 4);
        if (lo3 == 0)
            g[mrow * 128 + gcol] = gate * 0.125f;
    }
}

// Phase C body: apply via Horner for one wave handling `nm` m-rows starting
// at mbase, n fixed per lane-pair. (gw = global wave id, nm rows per wave)
template <int NM>
__device__ __forceinline__ void phaseC(int gw, int lane,
                                       const float* __restrict__ xr, const float* __restrict__ xi,
                                       const float* __restrict__ g, const float* __restrict__ Ac,
                                       float* __restrict__ outr, float* __restrict__ outi) {
    const int nl = lane >> 1, h = lane & 1;
    const int n = (gw & 3) * 32 + nl;
    const int mbase = (gw >> 2) * NM;

    float Ar_[4][8], Ai_[4][8];
    const float* An = Ac + n * 128;
    #pragma unroll
    for (int r = 0; r < 4; ++r) {
        const int o = h * 4 + r;
        #pragma unroll
        for (int p = 0; p < 2; ++p) {
            float4 f = *(const float4*)&An[o * 16 + h * 8 + p * 4];
            Ar_[r][p * 2]     = f.x;  Ai_[r][p * 2]     = f.y;
            Ar_[r][p * 2 + 1] = f.z;  Ai_[r][p * 2 + 1] = f.w;
        }
        #pragma unroll
        for (int p = 0; p < 2; ++p) {
            float4 f = *(const float4*)&An[o * 16 + (1 - h) * 8 + p * 4];
            Ar_[r][4 + p * 2]     = f.x;  Ai_[r][4 + p * 2]     = f.y;
            Ar_[r][4 + p * 2 + 1] = f.z;  Ai_[r][4 + p * 2 + 1] = f.w;
        }
    }

    #define CMV()                                                                   \
        {                                                                           \
            float pwr[4], pwi[4];                                                   \
            _Pragma("unroll")                                                       \
            for (int k2 = 0; k2 < 4; ++k2) {                                        \
                pwr[k2] = __shfl_xor(wr[k2], 1);                                    \
                pwi[k2] = __shfl_xor(wi[k2], 1);                                    \
            }                                                                       \
            _Pragma("unroll")                                                       \
            for (int r = 0; r < 4; ++r) {                                           \
                float sr = 0.f, si = 0.f;                                           \
                _Pragma("unroll")                                                   \
                for (int jj = 0; jj < 4; ++jj) {                                    \
                    sr += Ar_[r][jj] * wr[jj]      - Ai_[r][jj] * wi[jj];           \
                    si += Ar_[r][jj] * wi[jj]      + Ai_[r][jj] * wr[jj];           \
                    sr += Ar_[r][4 + jj] * pwr[jj] - Ai_[r][4 + jj] * pwi[jj];      \
                    si += Ar_[r][4 + jj] * pwi[jj] + Ai_[r][4 + jj] * pwr[jj];      \
                }                                                                   \
                tr[r] = sr; ti[r] = si;                                             \
            }                                                                       \
        }

    #pragma unroll
    for (int mi = 0; mi < NM; ++mi) {
        const int m = mbase + mi;
        const int d = n * 8 + h * 4;
        const float4 fvr = *(const float4*)&xr[m * 1024 + d];
        const float4 fvi = *(const float4*)&xi[m * 1024 + d];
        float vr[4] = {fvr.x, fvr.y, fvr.z, fvr.w};
        float vi[4] = {fvi.x, fvi.y, fvi.z, fvi.w};
        const float gv = g[m * 128 + n];
        const float c1 = -2.f * gv, c2 = -c1 * gv, c3 = -c2 * gv, c4 = -c3 * gv;
        float wr[4], wi[4], tr[4], ti[4];

        #pragma unroll
        for (int r = 0; r < 4; ++r) { wr[r] = c4 * vr[r]; wi[r] = c4 * vi[r]; }
        CMV();
        #pragma unroll
        for (int r = 0; r < 4; ++r) { wr[r] = c3 * vr[r] + tr[r]; wi[r] = c3 * vi[r] + ti[r]; }
        CMV();
        #pragma unroll
        for (int r = 0; r < 4; ++r) { wr[r] = c2 * vr[r] + tr[r]; wi[r] = c2 * vi[r] + ti[r]; }
        CMV();
        #pragma unroll
        for (int r = 0; r < 4; ++r) { wr[r] = c1 * vr[r] + tr[r]; wi[r] = c1 * vi[r] + ti[r]; }
        CMV();

        float4 s0 = {vr[0] + tr[0], vr[1] + tr[1], vr[2] + tr[2], vr[3] + tr[3]};
        float4 s1 = {vi[0] + ti[0], vi[1] + ti[1], vi[2] + ti[2], vi[3] + ti[3]};
        *(float4*)&outr[m * 1024 + d] = s0;
        *(float4*)&outi[m * 1024 + d] = s1;
    }
    #undef CMV
}

// ===========================================================================
// Cooperative mega kernel: 512 blocks x 256 threads, 64 KB LDS, <=2 blk/CU.
// ===========================================================================
__launch_bounds__(256, 2)
__global__ void mega_kernel(const float* __restrict__ xr, const float* __restrict__ xi,
                            const float* __restrict__ W,
                            const float* __restrict__ Ar, const float* __restrict__ Ai,
                            const float* __restrict__ bias,
                            signed char* __restrict__ xq, signed char* __restrict__ wq,
                            float* __restrict__ Ac, float* __restrict__ g,
                            float* __restrict__ outr, float* __restrict__ outi) {
    __shared__ __align__(16) signed char lA[4][64 * 128];   // 32 KB
    __shared__ __align__(16) signed char lB[4][64 * 128];   // 32 KB
    const int bid = blockIdx.x;
    const int tid = threadIdx.x;

    phaseA(bid * 256 + tid, xr, xi, W, Ar, Ai, xq, wq, Ac);
    __threadfence();
    cg::this_grid().sync();

    phaseB(bid, tid, lA, lB, xq, wq, bias, g);
    __threadfence();
    cg::this_grid().sync();

    const int gw = bid * 4 + (tid >> 6);     // 0..2047 -> 4 m-rows each
    phaseC<4>(gw, tid & 63, xr, xi, g, Ac, outr, outi);
}

// ===========================================================================
// Fallback path: the proven R12 three-kernel pipeline.
// ===========================================================================
__global__ void convert_kernel(const float* __restrict__ xr, const float* __restrict__ xi,
                               const float* __restrict__ W,
                               const float* __restrict__ Ar, const float* __restrict__ Ai,
                               signed char* __restrict__ xq, signed char* __restrict__ wq,
                               float* __restrict__ Ac) {
    // 512 blocks x 256 threads: same phaseA decomposition.
    phaseA(blockIdx.x * 256 + threadIdx.x, xr, xi, W, Ar, Ai, xq, wq, Ac);
}

__launch_bounds__(256, 2)
__global__ void gemm_gate_kernel(const signed char* __restrict__ A,
                                 const signed char* __restrict__ Bw,
                                 const float* __restrict__ bias,
                                 float* __restrict__ g) {
    __shared__ __align__(16) signed char lA[4][64 * 128];
    __shared__ __align__(16) signed char lB[4][64 * 128];
    phaseB(blockIdx.x, threadIdx.x, lA, lB, A, Bw, bias, g);
}

__launch_bounds__(256)
__global__ void apply_kernel(const float* __restrict__ xr, const float* __restrict__ xi,
                             const float* __restrict__ g, const float* __restrict__ Ac,
                             float* __restrict__ outr, float* __restrict__ outi) {
    const int gw = blockIdx.x * 4 + (threadIdx.x >> 6);   // 2048 waves
    phaseC<4>(gw, threadIdx.x & 63, xr, xi, g, Ac, outr, outi);
}

// ---------------------------------------------------------------------------
extern "C" void kernel_launch(void* const* d_in, const int* in_sizes, int n_in,
                              void* d_out, int out_size, void* d_ws, size_t ws_size,
                              hipStream_t stream) {
    const float* xr = (const float*)d_in[0];
    const float* xi = (const float*)d_in[1];
    const float* Ar = (const float*)d_in[2];
    const float* Ai = (const float*)d_in[3];
    const float* W  = (const float*)d_in[4];
    const float* bg = (const float*)d_in[5];
    float* out = (float*)d_out;

    char* ws = (char*)d_ws;
    signed char* xq = (signed char*)(ws);            // 4194304 B
    signed char* wq = (signed char*)(ws + 4194304);  // 2097152 B
    float*  g  = (float*)(ws + 6291456);             // 1048576 B
    float*  Ac = (float*)(ws + 7340032);             // 65536 B
    float* outr = out;
    float* outi = out + 2 * 1024 * 1024;

    void* args[] = {(void*)&xr, (void*)&xi, (void*)&W, (void*)&Ar, (void*)&Ai,
                    (void*)&bg, (void*)&xq, (void*)&wq, (void*)&Ac, (void*)&g,
                    (void*)&outr, (void*)&outi};
    hipError_t err = hipLaunchCooperativeKernel((const void*)mega_kernel,
                                                dim3(512), dim3(256), args, 0, stream);
    if (err != hipSuccess) {
        (void)hipGetLastError();   // clear the error; run the proven 3-kernel path
        hipLaunchKernelGGL(convert_kernel, dim3(512), dim3(256), 0, stream,
                           xr, xi, W, Ar, Ai, xq, wq, Ac);
        hipLaunchKernelGGL(gemm_gate_kernel, dim3(512), dim3(256), 0, stream,
                           xq, wq, bg, g);
        hipLaunchKernelGGL(apply_kernel, dim3(512), dim3(256), 0, stream,
                           xr, xi, g, Ac, outr, outi);
    }
}

// Round 16
// 45.403 us; speedup vs baseline: 6.1102x; 6.1102x over previous
//
#include <hip/hip_runtime.h>

#define GATE_SCALE 1.7015f
#define SX 32.0f
#define SW 1024.0f
#define DESCALE 3.0517578125e-05f   // 1/(SX*SW) = 2^-15

typedef __attribute__((ext_vector_type(4))) int   v4i;
typedef __attribute__((ext_vector_type(16))) int  v16i;

__device__ __forceinline__ int q8(float v, float s) {
    int q = __float2int_rn(v * s);
    return q < -127 ? -127 : (q > 127 ? 127 : q);
}

// ---------------------------------------------------------------------------
// Kernel 1: quantize x_cat and W to int8 in FRAGMENT-LINEAR layout + build Ac.
// Layout: panel g = row>>5 (32 rows), lo = row&31; 16B chunk kx = k>>4 stored
// at  g*65536 + (kx>>1)*1024 + (kx&1)*512 + lo*16  — so a wave's operand
// load (lane = lo + 32*hi reads chunk 2*kkk+hi of row lo) is ONE contiguous
// 1024-B global_load_dwordx4.
// ---------------------------------------------------------------------------
__global__ void convert_kernel(const float* __restrict__ xr, const float* __restrict__ xi,
                               const float* __restrict__ W,
                               const float* __restrict__ Ar, const float* __restrict__ Ai,
                               signed char* __restrict__ xqt, signed char* __restrict__ wqt,
                               float* __restrict__ Ac) {
    int bx = blockIdx.x;
    if (bx >= 1024) {
        int v = (bx - 1024) * 256 + threadIdx.x;   // 0..8191
        if (v < 8192) {
            int n = v >> 6, t = v & 63, o = t >> 3, i = t & 7;
            const float* arn = Ar + n * 64;
            const float* ain = Ai + n * 64;
            float a_r = 0.5f * (arn[o * 8 + i] - arn[i * 8 + o]);
            float a_i = 0.5f * (ain[o * 8 + i] + ain[i * 8 + o]);
            Ac[n * 128 + t * 2]     = a_r;
            Ac[n * 128 + t * 2 + 1] = a_i;
        }
        return;
    }
    const int XCV = 2048 * 2048 / 4;   // float4 groups for x_cat
    const int WV  = 1024 * 2048 / 4;
    const int STR = 1024 * 256;
    for (int v = bx * 256 + threadIdx.x; v < XCV + WV; v += STR) {
        float4 f;
        signed char* base;
        int row, k;
        float s;
        if (v < XCV) {
            int idx = v * 4;
            row = idx >> 11;
            k = idx & 2047;
            const float* src = (k < 1024) ? (xr + row * 1024 + k)
                                          : (xi + row * 1024 + k - 1024);
            f = *(const float4*)src;
            base = xqt;
            s = SX;
        } else {
            int idx = (v - XCV) * 4;
            row = idx >> 11;
            k = idx & 2047;
            f = *(const float4*)(W + row * 2048 + k);
            base = wqt;
            s = SW;
        }
        int a = q8(f.x, s), b = q8(f.y, s), c = q8(f.z, s), d = q8(f.w, s);
        unsigned int packed = (a & 0xFF) | ((b & 0xFF) << 8) | ((c & 0xFF) << 16)
                            | ((unsigned)(d & 0xFF) << 24);
        // fragment-linear address for (row, k..k+3):
        const int g = row >> 5, lo = row & 31;
        const int kx = k >> 4;                    // 16B chunk index
        const int off = g * 65536 + (kx >> 1) * 1024 + (kx & 1) * 512
                      + lo * 16 + (k & 15);
        *(unsigned int*)(base + off) = packed;
    }
}

// ---------------------------------------------------------------------------
// Kernel 2: i8 GEMM gate = sigmoid((x@W^T)*DESCALE + b)*1.7015 -> 8-col mean.
// ZERO LDS, ZERO barriers: fragment-linear layout makes every MFMA operand
// one coalesced 1024-B global load (L2-resident panels). 64 iterations of
// {2 loads + 1 mfma_i32_32x32x32_i8}, double-buffered groups of 4.
// Tile 64x64, 4 waves (2m x 2n, dup-2 -> paired-wave L1 hits), 512 blocks.
// XCD-rectangle swizzle keeps per-XCD working set at 2 MB (< 4 MB L2).
// ---------------------------------------------------------------------------
__launch_bounds__(256)
__global__ void gemm_gate_kernel(const signed char* __restrict__ At,  // xqt [64 panels][65536]
                                 const signed char* __restrict__ Bt,  // wqt [32 panels][65536]
                                 const float* __restrict__ bias,      // [1024]
                                 float* __restrict__ g) {             // [2048][128]
    const int tid = threadIdx.x;
    const int lane = tid & 63;
    const int wid = tid >> 6;                 // 0..3
    const int bid = blockIdx.x;
    const int x = bid & 7, l = bid >> 3;
    const int m0 = ((x & 3) * 8 + (l & 7)) * 64;
    const int n0 = ((x >> 2) * 8 + (l >> 3)) * 64;
    const int wr = wid >> 1, wc = wid & 1;
    const int lo = lane & 31, hi = lane >> 5, lo3 = lane & 7;

    const signed char* pa = At + ((m0 >> 5) + wr) * 65536 + lane * 16;
    const signed char* pb = Bt + ((n0 >> 5) + wc) * 65536 + lane * 16;

    v16i acc = {};
    v4i a0[4], b0[4], a1[4], b1[4];
    #pragma unroll
    for (int j = 0; j < 4; ++j) {
        a0[j] = *(const v4i*)(pa + j * 1024);
        b0[j] = *(const v4i*)(pb + j * 1024);
    }
    #pragma unroll
    for (int kp = 0; kp < 16; kp += 2) {
        // prefetch group kp+1 while computing group kp
        #pragma unroll
        for (int j = 0; j < 4; ++j) {
            a1[j] = *(const v4i*)(pa + ((kp + 1) * 4 + j) * 1024);
            b1[j] = *(const v4i*)(pb + ((kp + 1) * 4 + j) * 1024);
        }
        #pragma unroll
        for (int j = 0; j < 4; ++j)
            acc = __builtin_amdgcn_mfma_i32_32x32x32_i8(a0[j], b0[j], acc, 0, 0, 0);
        // prefetch group kp+2 while computing group kp+1
        if (kp < 14) {
            #pragma unroll
            for (int j = 0; j < 4; ++j) {
                a0[j] = *(const v4i*)(pa + ((kp + 2) * 4 + j) * 1024);
                b0[j] = *(const v4i*)(pb + ((kp + 2) * 4 + j) * 1024);
            }
        }
        #pragma unroll
        for (int j = 0; j < 4; ++j)
            acc = __builtin_amdgcn_mfma_i32_32x32x32_i8(a1[j], b1[j], acc, 0, 0, 0);
    }

    // Epilogue: C/D col = lane&31 (n), row = (r&3)+8*(r>>2)+4*hi (m-local).
    const int ncol = n0 + wc * 32 + lo;
    const float bv = bias[ncol];
    const int gcol = ncol >> 3;
    #pragma unroll
    for (int r = 0; r < 16; ++r) {
        const int mrow = m0 + wr * 32 + (r & 3) + 8 * (r >> 2) + 4 * hi;
        float z = ((float)acc[r] * DESCALE + bv) * GATE_SCALE;
        float gate = 1.0f / (1.0f + __expf(-z));
        gate += __shfl_xor(gate, 1);
        gate += __shfl_xor(gate, 2);
        gate += __shfl_xor(gate, 4);
        if (lo3 == 0)
            g[mrow * 128 + gcol] = gate * 0.125f;
    }
}

// ---------------------------------------------------------------------------
// Kernel 3: apply via Horner, zero LDS. Two lanes per site: lane h owns
// output rows h*4..h*4+3; A-block (4x8 complex) lives in 64 VGPRs, gathered
// once per block from L2-resident Ac. w-half exchanged via __shfl_xor(.,1)
// (DPP). x loads perfectly coalesced float4 (d = lane*4).
//   out = x + A(c1 x + A(c2 x + A(c3 x + A(c4 x)))),  c_k = 2(-g)^k
// ---------------------------------------------------------------------------
__launch_bounds__(256)
__global__ void apply_kernel(const float* __restrict__ xr, const float* __restrict__ xi,
                             const float* __restrict__ g,   // [2048][128]
                             const float* __restrict__ Ac,  // [128][64][2]
                             float* __restrict__ outr, float* __restrict__ outi) {
    const int tid = threadIdx.x;
    const int lane = tid & 63;
    const int wv = tid >> 6;
    const int nl = lane >> 1, h = lane & 1;
    const int n = blockIdx.x * 32 + nl;
    const int mbase = blockIdx.y * 8 + wv * 2;

    float Ar_[4][8], Ai_[4][8];
    const float* An = Ac + n * 128;
    #pragma unroll
    for (int r = 0; r < 4; ++r) {
        const int o = h * 4 + r;
        #pragma unroll
        for (int p = 0; p < 2; ++p) {
            float4 f = *(const float4*)&An[o * 16 + h * 8 + p * 4];
            Ar_[r][p * 2]     = f.x;  Ai_[r][p * 2]     = f.y;
            Ar_[r][p * 2 + 1] = f.z;  Ai_[r][p * 2 + 1] = f.w;
        }
        #pragma unroll
        for (int p = 0; p < 2; ++p) {
            float4 f = *(const float4*)&An[o * 16 + (1 - h) * 8 + p * 4];
            Ar_[r][4 + p * 2]     = f.x;  Ai_[r][4 + p * 2]     = f.y;
            Ar_[r][4 + p * 2 + 1] = f.z;  Ai_[r][4 + p * 2 + 1] = f.w;
        }
    }

    #define CMV()                                                                   \
        {                                                                           \
            float pwr[4], pwi[4];                                                   \
            _Pragma("unroll")                                                       \
            for (int k2 = 0; k2 < 4; ++k2) {                                        \
                pwr[k2] = __shfl_xor(wr[k2], 1);                                    \
                pwi[k2] = __shfl_xor(wi[k2], 1);                                    \
            }                                                                       \
            _Pragma("unroll")                                                       \
            for (int r = 0; r < 4; ++r) {                                           \
                float sr = 0.f, si = 0.f;                                           \
                _Pragma("unroll")                                                   \
                for (int jj = 0; jj < 4; ++jj) {                                    \
                    sr += Ar_[r][jj] * wr[jj]      - Ai_[r][jj] * wi[jj];           \
                    si += Ar_[r][jj] * wi[jj]      + Ai_[r][jj] * wr[jj];           \
                    sr += Ar_[r][4 + jj] * pwr[jj] - Ai_[r][4 + jj] * pwi[jj];      \
                    si += Ar_[r][4 + jj] * pwi[jj] + Ai_[r][4 + jj] * pwr[jj];      \
                }                                                                   \
                tr[r] = sr; ti[r] = si;                                             \
            }                                                                       \
        }

    #pragma unroll
    for (int mi = 0; mi < 2; ++mi) {
        const int m = mbase + mi;
        const int d = n * 8 + h * 4;
        const float4 fvr = *(const float4*)&xr[m * 1024 + d];
        const float4 fvi = *(const float4*)&xi[m * 1024 + d];
        float vr[4] = {fvr.x, fvr.y, fvr.z, fvr.w};
        float vi[4] = {fvi.x, fvi.y, fvi.z, fvi.w};
        const float gv = g[m * 128 + n];
        const float c1 = -2.f * gv, c2 = -c1 * gv, c3 = -c2 * gv, c4 = -c3 * gv;
        float wr[4], wi[4], tr[4], ti[4];

        #pragma unroll
        for (int r = 0; r < 4; ++r) { wr[r] = c4 * vr[r]; wi[r] = c4 * vi[r]; }
        CMV();
        #pragma unroll
        for (int r = 0; r < 4; ++r) { wr[r] = c3 * vr[r] + tr[r]; wi[r] = c3 * vi[r] + ti[r]; }
        CMV();
        #pragma unroll
        for (int r = 0; r < 4; ++r) { wr[r] = c2 * vr[r] + tr[r]; wi[r] = c2 * vi[r] + ti[r]; }
        CMV();
        #pragma unroll
        for (int r = 0; r < 4; ++r) { wr[r] = c1 * vr[r] + tr[r]; wi[r] = c1 * vi[r] + ti[r]; }
        CMV();

        float4 s0 = {vr[0] + tr[0], vr[1] + tr[1], vr[2] + tr[2], vr[3] + tr[3]};
        float4 s1 = {vi[0] + ti[0], vi[1] + ti[1], vi[2] + ti[2], vi[3] + ti[3]};
        *(float4*)&outr[m * 1024 + d] = s0;
        *(float4*)&outi[m * 1024 + d] = s1;
    }
    #undef CMV
}

// ---------------------------------------------------------------------------
extern "C" void kernel_launch(void* const* d_in, const int* in_sizes, int n_in,
                              void* d_out, int out_size, void* d_ws, size_t ws_size,
                              hipStream_t stream) {
    const float* xr = (const float*)d_in[0];
    const float* xi = (const float*)d_in[1];
    const float* Ar = (const float*)d_in[2];
    const float* Ai = (const float*)d_in[3];
    const float* W  = (const float*)d_in[4];
    const float* bg = (const float*)d_in[5];
    float* out = (float*)d_out;

    char* ws = (char*)d_ws;
    signed char* xqt = (signed char*)(ws);            // 64 panels * 65536 = 4194304 B
    signed char* wqt = (signed char*)(ws + 4194304);  // 32 panels * 65536 = 2097152 B
    float*  g  = (float*)(ws + 6291456);              // 2048*128*4 = 1048576 B
    float*  Ac = (float*)(ws + 7340032);              // 128*128*4  = 65536 B

    hipLaunchKernelGGL(convert_kernel, dim3(1056), dim3(256), 0, stream,
                       xr, xi, W, Ar, Ai, xqt, wqt, Ac);
    hipLaunchKernelGGL(gemm_gate_kernel, dim3(512), dim3(256), 0, stream, xqt, wqt, bg, g);
    hipLaunchKernelGGL(apply_kernel, dim3(4, 256), dim3(256), 0, stream,
                       xr, xi, g, Ac, out, out + 2 * 1024 * 1024);
}

// Round 17
// 35.013 us; speedup vs baseline: 7.9233x; 1.2967x over previous
//
#include <hip/hip_runtime.h>

#define GATE_SCALE 1.7015f
#define SX 32.0f
#define SW 1024.0f
#define DESCALE 3.0517578125e-05f   // 1/(SX*SW) = 2^-15

typedef __attribute__((ext_vector_type(4))) int   v4i;
typedef __attribute__((ext_vector_type(16))) int  v16i;

__device__ __forceinline__ void gl2lds16(const void* g, void* l) {
    __builtin_amdgcn_global_load_lds((const __attribute__((address_space(1))) void*)g,
                                     (__attribute__((address_space(3))) void*)l, 16, 0, 0);
}

__device__ __forceinline__ int q8(float v, float s) {
    int q = __float2int_rn(v * s);
    return q < -127 ? -127 : (q > 127 ? 127 : q);
}

// ---------------------------------------------------------------------------
// Kernel 1: quantize x_cat and W to int8 + build antisymmetrized complex A.
// ---------------------------------------------------------------------------
__global__ void convert_kernel(const float* __restrict__ xr, const float* __restrict__ xi,
                               const float* __restrict__ W,
                               const float* __restrict__ Ar, const float* __restrict__ Ai,
                               signed char* __restrict__ xq, signed char* __restrict__ wq,
                               float* __restrict__ Ac) {
    int bx = blockIdx.x;
    if (bx >= 1024) {
        int v = (bx - 1024) * 256 + threadIdx.x;   // 0..8191
        if (v < 8192) {
            int n = v >> 6, t = v & 63, o = t >> 3, i = t & 7;
            const float* arn = Ar + n * 64;
            const float* ain = Ai + n * 64;
            float a_r = 0.5f * (arn[o * 8 + i] - arn[i * 8 + o]);
            float a_i = 0.5f * (ain[o * 8 + i] + ain[i * 8 + o]);
            Ac[n * 128 + t * 2]     = a_r;
            Ac[n * 128 + t * 2 + 1] = a_i;
        }
        return;
    }
    const int XCV = 2048 * 2048 / 4;
    const int WV  = 1024 * 2048 / 4;
    const int STR = 1024 * 256;
    for (int v = bx * 256 + threadIdx.x; v < XCV + WV; v += STR) {
        float4 f;
        signed char* dst;
        float s;
        if (v < XCV) {
            int idx = v * 4;
            int m = idx >> 11;
            int k = idx & 2047;
            const float* src = (k < 1024) ? (xr + m * 1024 + k)
                                          : (xi + m * 1024 + k - 1024);
            f = *(const float4*)src;
            dst = xq + idx;
            s = SX;
        } else {
            int idx = (v - XCV) * 4;
            f = *(const float4*)(W + idx);
            dst = wq + idx;
            s = SW;
        }
        int a = q8(f.x, s), b = q8(f.y, s), c = q8(f.z, s), d = q8(f.w, s);
        unsigned int packed = (a & 0xFF) | ((b & 0xFF) << 8) | ((c & 0xFF) << 16)
                            | ((unsigned)(d & 0xFF) << 24);
        *(unsigned int*)dst = packed;
    }
}

// ---------------------------------------------------------------------------
// Kernel 2: FUSED i8 GEMM + gate + apply.
// GEMM part = R12's proven body: 64x64 tile, BK=128B, 4 waves (2x2), ring-4
// LDS, counted vmcnt(8), raw barriers, setprio, XCD-rectangle swizzle.
// Epilogue: gate -> LDS (2 KB in lA[0], unread since TILE(12)), barrier,
// then apply: each thread handles the h-half of 4 sites (mloc = mb+{0,16,
// 32,48}, fixed n); partner lane = t^1 (same wave) for the w-half exchange.
// Deletes the apply dispatch and the g global round-trip.
// ---------------------------------------------------------------------------
__launch_bounds__(256, 2)
__global__ void gemm_apply_kernel(const signed char* __restrict__ A,   // xq [2048][2048]
                                  const signed char* __restrict__ Bw,  // wq [1024][2048]
                                  const float* __restrict__ bias,      // [1024]
                                  const float* __restrict__ xr, const float* __restrict__ xi,
                                  const float* __restrict__ Ac,        // [128][64][2]
                                  float* __restrict__ outr, float* __restrict__ outi) {
    __shared__ __align__(16) signed char lA[4][64 * 128];   // 32 KB
    __shared__ __align__(16) signed char lB[4][64 * 128];   // 32 KB
    const int tid = threadIdx.x;
    const int lane = tid & 63;
    const int wid = tid >> 6;                 // 0..3
    const int bid = blockIdx.x;
    const int x = bid & 7, l = bid >> 3;
    const int m0 = ((x & 3) * 8 + (l & 7)) * 64;
    const int n0 = ((x >> 2) * 8 + (l >> 3)) * 64;
    const int wr = wid >> 1, wc = wid & 1;
    const int lo = lane & 31, hi = lane >> 5, lo3 = lane & 7;
    const int arow = wr * 32 + lo, brow = wc * 32 + lo;
    const int ar7 = arow & 7, br7 = brow & 7;

    v16i acc = {};

    #define STAGE(buf, k0)                                                          \
        {                                                                           \
            _Pragma("unroll")                                                       \
            for (int q = 0; q < 2; ++q) {                                           \
                int c = q * 256 + tid;                                              \
                int row = c >> 3, ks = (c & 7) ^ (row & 7);                         \
                gl2lds16(&A[(m0 + row) * 2048 + (k0) + ks * 16], &lA[buf][c * 16]); \
            }                                                                       \
            _Pragma("unroll")                                                       \
            for (int q = 0; q < 2; ++q) {                                           \
                int c = q * 256 + tid;                                              \
                int row = c >> 3, ks = (c & 7) ^ (row & 7);                         \
                gl2lds16(&Bw[(n0 + row) * 2048 + (k0) + ks * 16], &lB[buf][c * 16]);\
            }                                                                       \
        }

    #define TILE(t, vmstr, do_stage)                                               \
        {                                                                           \
            asm volatile("s_waitcnt vmcnt(" vmstr ")" ::: "memory");                \
            __builtin_amdgcn_s_barrier();                                           \
            const int b = (t) & 3;                                                  \
            v4i af[4], bf[4];                                                       \
            _Pragma("unroll")                                                       \
            for (int kk = 0; kk < 4; ++kk) {                                        \
                const int ch = ((2 * kk + hi) ^ ar7) << 4;                          \
                const int chb = ((2 * kk + hi) ^ br7) << 4;                         \
                af[kk] = *(const v4i*)&lA[b][arow * 128 + ch];                      \
                bf[kk] = *(const v4i*)&lB[b][brow * 128 + chb];                     \
            }                                                                       \
            if (do_stage) STAGE((((t) + 3) & 3), ((t) + 3) * 128);                  \
            __builtin_amdgcn_s_setprio(1);                                          \
            _Pragma("unroll")                                                       \
            for (int kk = 0; kk < 4; ++kk)                                          \
                acc = __builtin_amdgcn_mfma_i32_32x32x32_i8(af[kk], bf[kk], acc, 0, 0, 0); \
            __builtin_amdgcn_s_setprio(0);                                          \
        }

    STAGE(0, 0);
    STAGE(1, 128);
    STAGE(2, 256);
    for (int t = 0; t < 13; ++t) TILE(t, "8", true);
    TILE(13, "8", false);
    TILE(14, "4", false);
    TILE(15, "0", false);
    #undef TILE
    #undef STAGE

    // ---- gate epilogue -> LDS (reuse lA[0]: no wave reads it after TILE 12,
    // and every wave is past barrier-15 before these writes) ----
    float* lds_g = (float*)&lA[0][0];        // [64 m-local][8 gcol-local]
    {
        const int ncol = n0 + wc * 32 + lo;
        const float bv = bias[ncol];
        const int gl = wc * 4 + (lo >> 3);   // gcol-local 0..7
        #pragma unroll
        for (int r = 0; r < 16; ++r) {
            const int mloc = wr * 32 + (r & 3) + 8 * (r >> 2) + 4 * hi;
            float z = ((float)acc[r] * DESCALE + bv) * GATE_SCALE;
            float gate = 1.0f / (1.0f + __expf(-z));
            gate += __shfl_xor(gate, 1);
            gate += __shfl_xor(gate, 2);
            gate += __shfl_xor(gate, 4);
            if (lo3 == 0)
                lds_g[mloc * 8 + gl] = gate * 0.125f;
        }
    }
    __syncthreads();

    // ---- apply: thread t -> h = t&1, j = (t>>1)&7, mb = t>>4 (0..15);
    // sites (m0 + mb + {0,16,32,48}, n = n0/8 + j), h-half rows. ----
    {
        const int h = tid & 1, j = (tid >> 1) & 7, mb = tid >> 4;
        const int n = (n0 >> 3) + j;

        float Ar_[4][8], Ai_[4][8];
        const float* An = Ac + n * 128;
        #pragma unroll
        for (int r = 0; r < 4; ++r) {
            const int o = h * 4 + r;
            #pragma unroll
            for (int p = 0; p < 2; ++p) {
                float4 f = *(const float4*)&An[o * 16 + h * 8 + p * 4];
                Ar_[r][p * 2]     = f.x;  Ai_[r][p * 2]     = f.y;
                Ar_[r][p * 2 + 1] = f.z;  Ai_[r][p * 2 + 1] = f.w;
            }
            #pragma unroll
            for (int p = 0; p < 2; ++p) {
                float4 f = *(const float4*)&An[o * 16 + (1 - h) * 8 + p * 4];
                Ar_[r][4 + p * 2]     = f.x;  Ai_[r][4 + p * 2]     = f.y;
                Ar_[r][4 + p * 2 + 1] = f.z;  Ai_[r][4 + p * 2 + 1] = f.w;
            }
        }

        #define CMV()                                                                   \
            {                                                                           \
                float pwr[4], pwi[4];                                                   \
                _Pragma("unroll")                                                       \
                for (int k2 = 0; k2 < 4; ++k2) {                                        \
                    pwr[k2] = __shfl_xor(wr[k2], 1);                                    \
                    pwi[k2] = __shfl_xor(wi[k2], 1);                                    \
                }                                                                       \
                _Pragma("unroll")                                                       \
                for (int r = 0; r < 4; ++r) {                                           \
                    float sr = 0.f, si = 0.f;                                           \
                    _Pragma("unroll")                                                   \
                    for (int jj = 0; jj < 4; ++jj) {                                    \
                        sr += Ar_[r][jj] * wr[jj]      - Ai_[r][jj] * wi[jj];           \
                        si += Ar_[r][jj] * wi[jj]      + Ai_[r][jj] * wr[jj];           \
                        sr += Ar_[r][4 + jj] * pwr[jj] - Ai_[r][4 + jj] * pwi[jj];      \
                        si += Ar_[r][4 + jj] * pwi[jj] + Ai_[r][4 + jj] * pwr[jj];      \
                    }                                                                   \
                    tr[r] = sr; ti[r] = si;                                             \
                }                                                                       \
            }

        #pragma unroll
        for (int mi = 0; mi < 4; ++mi) {
            const int mloc = mb + mi * 16;
            const int m = m0 + mloc;
            const int d = n * 8 + h * 4;
            const float4 fvr = *(const float4*)&xr[m * 1024 + d];
            const float4 fvi = *(const float4*)&xi[m * 1024 + d];
            float vr[4] = {fvr.x, fvr.y, fvr.z, fvr.w};
            float vi[4] = {fvi.x, fvi.y, fvi.z, fvi.w};
            const float gv = lds_g[mloc * 8 + j];
            const float c1 = -2.f * gv, c2 = -c1 * gv, c3 = -c2 * gv, c4 = -c3 * gv;
            float wr[4], wi[4], tr[4], ti[4];

            #pragma unroll
            for (int r = 0; r < 4; ++r) { wr[r] = c4 * vr[r]; wi[r] = c4 * vi[r]; }
            CMV();
            #pragma unroll
            for (int r = 0; r < 4; ++r) { wr[r] = c3 * vr[r] + tr[r]; wi[r] = c3 * vi[r] + ti[r]; }
            CMV();
            #pragma unroll
            for (int r = 0; r < 4; ++r) { wr[r] = c2 * vr[r] + tr[r]; wi[r] = c2 * vi[r] + ti[r]; }
            CMV();
            #pragma unroll
            for (int r = 0; r < 4; ++r) { wr[r] = c1 * vr[r] + tr[r]; wi[r] = c1 * vi[r] + ti[r]; }
            CMV();

            float4 s0 = {vr[0] + tr[0], vr[1] + tr[1], vr[2] + tr[2], vr[3] + tr[3]};
            float4 s1 = {vi[0] + ti[0], vi[1] + ti[1], vi[2] + ti[2], vi[3] + ti[3]};
            *(float4*)&outr[m * 1024 + d] = s0;
            *(float4*)&outi[m * 1024 + d] = s1;
        }
        #undef CMV
    }
}

// ---------------------------------------------------------------------------
extern "C" void kernel_launch(void* const* d_in, const int* in_sizes, int n_in,
                              void* d_out, int out_size, void* d_ws, size_t ws_size,
                              hipStream_t stream) {
    const float* xr = (const float*)d_in[0];
    const float* xi = (const float*)d_in[1];
    const float* Ar = (const float*)d_in[2];
    const float* Ai = (const float*)d_in[3];
    const float* W  = (const float*)d_in[4];
    const float* bg = (const float*)d_in[5];
    float* out = (float*)d_out;

    char* ws = (char*)d_ws;
    signed char* xq = (signed char*)(ws);            // 4194304 B
    signed char* wq = (signed char*)(ws + 4194304);  // 2097152 B
    float*  Ac = (float*)(ws + 6291456);             // 65536 B

    hipLaunchKernelGGL(convert_kernel, dim3(1056), dim3(256), 0, stream,
                       xr, xi, W, Ar, Ai, xq, wq, Ac);
    hipLaunchKernelGGL(gemm_apply_kernel, dim3(512), dim3(256), 0, stream,
                       xq, wq, bg, xr, xi, Ac, out, out + 2 * 1024 * 1024);
}